// Round 8
// baseline (1226.641 us; speedup 1.0000x reference)
//
#include <hip/hip_runtime.h>
#include <hip/hip_cooperative_groups.h>
#include <math.h>

#define DM 3136
#define DH 512

typedef __attribute__((ext_vector_type(8))) short bf16x8;
typedef __attribute__((ext_vector_type(4))) float f32x4;

__device__ __forceinline__ ushort f2bf(float f) {
  union { float f; unsigned u; } v; v.f = f;
  unsigned r = v.u + 0x7FFFu + ((v.u >> 16) & 1u);
  return (ushort)(r >> 16);
}

#define MICRO_4x4 \
    acc[0][0] += a.x*b.x; acc[0][1] += a.x*b.y; acc[0][2] += a.x*b.z; acc[0][3] += a.x*b.w; \
    acc[1][0] += a.y*b.x; acc[1][1] += a.y*b.y; acc[1][2] += a.y*b.z; acc[1][3] += a.y*b.w; \
    acc[2][0] += a.z*b.x; acc[2][1] += a.z*b.y; acc[2][2] += a.z*b.z; acc[2][3] += a.z*b.w; \
    acc[3][0] += a.w*b.x; acc[3][1] += a.w*b.y; acc[3][2] += a.w*b.z; acc[3][3] += a.w*b.w;

// ---------------- gelu ----------------
__device__ __forceinline__ void gelu_both(float xx, float& g, float& gp) {
  const float c = 0.7978845608028654f;
  const float a = 0.044715f;
  float x2 = xx * xx;
  float u = c * (xx + a * xx * x2);
  float t = tanhf(u);
  g  = 0.5f * xx * (1.f + t);
  gp = 0.5f * (1.f + t) + 0.5f * xx * (1.f - t * t) * c * (1.f + 3.f * a * x2);
}
__device__ __forceinline__ float gelu_only(float xx) {
  const float c = 0.7978845608028654f;
  const float a = 0.044715f;
  float u = c * (xx + a * xx * xx * xx);
  return 0.5f * xx * (1.f + tanhf(u));
}

// ---------------- nt64 MFMA core: C[i,j] += sum_k A[i,k]*B[j,k] ----------------
__device__ __forceinline__ void nt64_core(
    const ushort* __restrict__ A, int lda,
    const ushort* __restrict__ B, int ldb,
    int ksteps, f32x4* acc) {
  int lane = threadIdx.x & 63;
  int wv = threadIdx.x >> 6;
  int qr = wv >> 1, qc = wv & 1;
  int lr = lane & 15;
  int lk = (lane >> 4) << 3;
  const ushort* pa0 = A + (size_t)(qr * 32 + lr) * lda + lk;
  const ushort* pa1 = pa0 + (size_t)16 * lda;
  const ushort* pb0 = B + (size_t)(qc * 32 + lr) * ldb + lk;
  const ushort* pb1 = pb0 + (size_t)16 * ldb;
  bf16x8 a0 = *(const bf16x8*)pa0;
  bf16x8 a1 = *(const bf16x8*)pa1;
  bf16x8 b0 = *(const bf16x8*)pb0;
  bf16x8 b1 = *(const bf16x8*)pb1;
  for (int s = 0; s < ksteps; ++s) {
    int sn = (s + 1 < ksteps) ? (s + 1) * 32 : s * 32;
    bf16x8 na0 = *(const bf16x8*)(pa0 + sn);
    bf16x8 na1 = *(const bf16x8*)(pa1 + sn);
    bf16x8 nb0 = *(const bf16x8*)(pb0 + sn);
    bf16x8 nb1 = *(const bf16x8*)(pb1 + sn);
    acc[0] = __builtin_amdgcn_mfma_f32_16x16x32_bf16(a0, b0, acc[0], 0, 0, 0);
    acc[1] = __builtin_amdgcn_mfma_f32_16x16x32_bf16(a0, b1, acc[1], 0, 0, 0);
    acc[2] = __builtin_amdgcn_mfma_f32_16x16x32_bf16(a1, b0, acc[2], 0, 0, 0);
    acc[3] = __builtin_amdgcn_mfma_f32_16x16x32_bf16(a1, b1, acc[3], 0, 0, 0);
    a0 = na0; a1 = na1; b0 = nb0; b1 = nb1;
  }
}

__device__ __forceinline__ void nt64_store(const f32x4* acc, float* __restrict__ dst, int ldc) {
  int lane = threadIdx.x & 63, wv = threadIdx.x >> 6;
  int r0 = (wv >> 1) * 32 + ((lane >> 4) << 2);
  int c0 = (wv & 1) * 32 + (lane & 15);
  #pragma unroll
  for (int r = 0; r < 4; ++r) {
    dst[(size_t)(r0 + r) * ldc + c0]           = acc[0][r];
    dst[(size_t)(r0 + r) * ldc + c0 + 16]      = acc[1][r];
    dst[(size_t)(r0 + r + 16) * ldc + c0]      = acc[2][r];
    dst[(size_t)(r0 + r + 16) * ldc + c0 + 16] = acc[3][r];
  }
}

// Dw epilogue (256 active threads): dw = wc2*(acc + b2in - V);
// bf16 both layouts + b2out = b2in - colsum
__device__ __forceinline__ void dw_epilogue256(
    const f32x4* acc, int n0, const float* __restrict__ Vn,
    const float* __restrict__ b2in, float wc2,
    ushort* __restrict__ Dwb_o, ushort* __restrict__ Dwt_o,
    float* __restrict__ b2out, float* smem) {
  int lane = threadIdx.x & 63, wvv = threadIdx.x >> 6;
  int qr = wvv >> 1, qc = wvv & 1;
  int r0 = qr * 32 + ((lane >> 4) << 2);
  int c0 = qc * 32 + (lane & 15);
  float csum[2] = {0.f, 0.f};
  #pragma unroll
  for (int r = 0; r < 4; ++r) {
    #pragma unroll
    for (int p = 0; p < 4; ++p) {
      int m = r0 + r + ((p >> 1) ? 16 : 0);
      int dl = c0 + ((p & 1) ? 16 : 0);
      int d = n0 + dl;
      float dw = wc2 * (acc[p][r] + b2in[d] - Vn[(size_t)m * DM + d]);
      ushort db = f2bf(dw);
      Dwb_o[(size_t)m * DM + d] = db;
      Dwt_o[(size_t)d * 64 + m] = db;
      csum[p & 1] += dw;
    }
  }
  int slot = qr * 4 + ((lane >> 4) & 3);
  smem[(size_t)c0 * 8 + slot] = csum[0];
  smem[(size_t)(c0 + 16) * 8 + slot] = csum[1];
  __syncthreads();
  if (threadIdx.x < 64) {
    float s = 0.f;
    #pragma unroll
    for (int q = 0; q < 8; ++q) s += smem[threadIdx.x * 8 + q];
    b2out[n0 + threadIdx.x] = b2in[n0 + threadIdx.x] - s;
  }
}

// ---------------- conv3x3 + RMSNorm + W1/W2 bf16 prep tails ----------------
__global__ __launch_bounds__(256) void conv_rms(
    const float* __restrict__ x,
    const float* __restrict__ wk, const float* __restrict__ bk,
    const float* __restrict__ wv, const float* __restrict__ bv,
    const float* __restrict__ sk, const float* __restrict__ sv,
    const float* __restrict__ W1, ushort* __restrict__ w1tb,
    const float* __restrict__ W2, ushort* __restrict__ W2b0, ushort* __restrict__ W2tb0,
    ushort* __restrict__ nkb, float* __restrict__ nv) {
  __shared__ float smem[4160];
  int tid = threadIdx.x;
  if (blockIdx.x >= 1960) {
    int t = blockIdx.x - 1960;           // 0..391
    int d0 = (t % 49) * 64, h0 = (t / 49) * 64;
    int c = tid & 63, rq = tid >> 6;
    #pragma unroll
    for (int q = 0; q < 16; ++q) {
      int r = q * 4 + rq;
      float v = W2[(size_t)(h0 + r) * DM + d0 + c];
      smem[r * 65 + c] = v;
      W2b0[(size_t)(h0 + r) * DM + d0 + c] = f2bf(v);
    }
    __syncthreads();
    #pragma unroll
    for (int q = 0; q < 16; ++q) {
      int r = q * 4 + rq;
      W2tb0[(size_t)(d0 + r) * DH + h0 + c] = f2bf(smem[c * 65 + r]);
    }
    return;
  }
  if (blockIdx.x >= 1568) {
    int t = blockIdx.x - 1568;           // 0..391
    int d0 = (t % 49) * 64, h0 = (t / 49) * 64;
    int c = tid & 63, rq = tid >> 6;
    #pragma unroll
    for (int q = 0; q < 16; ++q) {
      int r = q * 4 + rq;
      smem[r * 65 + c] = W1[(size_t)(d0 + r) * 512 + h0 + c];
    }
    __syncthreads();
    #pragma unroll
    for (int q = 0; q < 16; ++q) {
      int r = q * 4 + rq;
      w1tb[(size_t)(h0 + r) * 3136 + d0 + c] = f2bf(smem[c * 65 + r]);
    }
    return;
  }
  float* swk = smem;
  float* swv = smem + 144;
  float* sb  = smem + 288;
  if (tid < 144) { swk[tid] = wk[tid]; swv[tid] = wv[tid]; }
  if (tid < 4) {
    sb[tid] = bk[tid]; sb[4 + tid] = bv[tid];
    sb[8 + tid] = sk[tid]; sb[12 + tid] = sv[tid];
  }
  __syncthreads();
  int idx = blockIdx.x * 256 + tid;
  int t = idx / 784, hw = idx - t * 784;
  int h = hw / 28, w = hw - h * 28;
  float ak[4], av[4];
  #pragma unroll
  for (int c = 0; c < 4; ++c) { ak[c] = sb[c]; av[c] = sb[4 + c]; }
  const float* xt = x + (size_t)t * DM;
  for (int kh = 0; kh < 3; ++kh) {
    int ih = h + kh - 1;
    if (ih < 0 || ih >= 28) continue;
    for (int kw = 0; kw < 3; ++kw) {
      int iw = w + kw - 1;
      if (iw < 0 || iw >= 28) continue;
      int base = (kh * 3 + kw) * 16;
      #pragma unroll
      for (int ci = 0; ci < 4; ++ci) {
        float xv = xt[ci * 784 + ih * 28 + iw];
        #pragma unroll
        for (int co = 0; co < 4; ++co) {
          ak[co] += xv * swk[base + ci * 4 + co];
          av[co] += xv * swv[base + ci * 4 + co];
        }
      }
    }
  }
  float mk = (ak[0]*ak[0] + ak[1]*ak[1] + ak[2]*ak[2] + ak[3]*ak[3]) * 0.25f + 1e-6f;
  float mv = (av[0]*av[0] + av[1]*av[1] + av[2]*av[2] + av[3]*av[3]) * 0.25f + 1e-6f;
  float ik = 1.f / sqrtf(mk), iv = 1.f / sqrtf(mv);
  ushort4 ok = { f2bf(ak[0]*ik*sb[8]), f2bf(ak[1]*ik*sb[9]),
                 f2bf(ak[2]*ik*sb[10]), f2bf(ak[3]*ik*sb[11]) };
  float4 ov = { av[0]*iv*sb[12], av[1]*iv*sb[13], av[2]*iv*sb[14], av[3]*iv*sb[15] };
  *(ushort4*)&nkb[(size_t)idx * 4] = ok;
  *(float4*)&nv[(size_t)idx * 4] = ov;
}

// ---------------- u1: KK + Hb slices (bf16 MFMA NT) ----------------
__global__ __launch_bounds__(256) void u1_kernel(
    const ushort* __restrict__ nkb, const ushort* __restrict__ w1tb,
    float* __restrict__ KKsl, float* __restrict__ Hb_sl) {
  f32x4 acc[4] = {{0.f,0.f,0.f,0.f},{0.f,0.f,0.f,0.f},{0.f,0.f,0.f,0.f},{0.f,0.f,0.f,0.f}};
  int job = blockIdx.x;
  if (job < 448) {
    int s = job % 7;
    int t = job / 7;
    int m0 = (t >> 3) * 64, n0 = (t & 7) * 64;
    nt64_core(nkb + (size_t)m0 * DM + s * 448, DM, w1tb + (size_t)n0 * DM + s * 448, DM, 14, acc);
    nt64_store(acc, Hb_sl + (size_t)s * 262144 + (size_t)m0 * 512 + n0, 512);
  } else {
    int j2 = job - 448;
    int p = j2 / 7, s = j2 % 7;
    int c = 0;
    while ((c + 1) * (c + 2) / 2 <= p) ++c;
    int j = p - c * (c + 1) / 2;
    nt64_core(nkb + (size_t)c * 64 * DM + s * 448, DM, nkb + (size_t)j * 64 * DM + s * 448, DM, 14, acc);
    nt64_store(acc, KKsl + ((size_t)p * 7 + s) * 4096, 64);
  }
}

// u2: KKf (sum 7) + Hbase (sum 7) + fused hred for chunk 0
__global__ __launch_bounds__(256) void u2_kernel(
    const float* __restrict__ KKsl, const float* __restrict__ Hb_sl,
    float* __restrict__ KKf, float* __restrict__ Hbase,
    const float* __restrict__ b1,
    float* __restrict__ Hh, ushort* __restrict__ Gb, ushort* __restrict__ Gtb,
    float* __restrict__ Gp) {
  int i = blockIdx.x * 256 + threadIdx.x;
  if (i < 147456) {
    int pair = i >> 12, e = i & 4095;
    float s = 0.f;
    #pragma unroll
    for (int t = 0; t < 7; ++t) s += KKsl[((size_t)pair * 7 + t) * 4096 + e];
    KKf[i] = s;
  } else {
    int j = i - 147456;   // < 262144
    float s = 0.f;
    #pragma unroll
    for (int t = 0; t < 7; ++t) s += Hb_sl[(size_t)t * 262144 + j];
    Hbase[j] = s;
    if (j < 32768) {
      Hh[j] = s;
      float g, gp;
      gelu_both(s + b1[j & 511], g, gp);
      Gb[j] = f2bf(g);
      Gtb[(j & 511) * 64 + (j >> 9)] = f2bf(g);
      Gp[j] = gp;
    }
  }
}

// ---------------- hs_corr (fp32, for pipelined future Hcorr) ----------------
__device__ __forceinline__ void hs_corr_job(
    const float* __restrict__ KK, const float* __restrict__ Ewj,
    float* __restrict__ dst, int bx, float* smem) {
  float* As = smem;
  float* Bs = smem + 4096;
  int tid = threadIdx.x;
  int n0 = bx * 64;
  {
    int m = tid >> 2, ib = (tid & 3) * 16;
    #pragma unroll
    for (int q = 0; q < 4; ++q) {
      float4 v = *(const float4*)(KK + m * 64 + ib + q * 4);
      As[(ib + q*4 + 0)*64 + m] = v.x;
      As[(ib + q*4 + 1)*64 + m] = v.y;
      As[(ib + q*4 + 2)*64 + m] = v.z;
      As[(ib + q*4 + 3)*64 + m] = v.w;
    }
    int kr = tid >> 4, nn = (tid & 15) * 4;
    #pragma unroll
    for (int q = 0; q < 4; ++q)
      *(float4*)&Bs[(kr + q*16)*64 + nn] = *(const float4*)(Ewj + (size_t)(kr + q*16) * DH + n0 + nn);
  }
  __syncthreads();
  int tx = tid & 15, ty = tid >> 4;
  float acc[4][4] = {{0.f}};
  #pragma unroll 16
  for (int kk = 0; kk < 64; ++kk) {
    float4 a = *(const float4*)&As[kk*64 + ty * 4];
    float4 b = *(const float4*)&Bs[kk*64 + tx * 4];
    MICRO_4x4
  }
  #pragma unroll
  for (int r = 0; r < 4; ++r) {
    float4 v = { acc[r][0], acc[r][1], acc[r][2], acc[r][3] };
    *(float4*)&dst[(ty*4 + r) * DH + n0 + tx*4] = v;
  }
}

// ---------------- pred0: chunk-0 prediction -> Dw_0 + b2_0 ----------------
__global__ __launch_bounds__(256) void pred0_kernel(
    const ushort* __restrict__ Gb0, const ushort* __restrict__ W2tb0,
    const float* __restrict__ V, const float* __restrict__ b2in, float wc2,
    float* __restrict__ b2out, ushort* __restrict__ Dwb_o, ushort* __restrict__ Dwt_o) {
  __shared__ float smem[512];
  f32x4 acc[4] = {{0.f,0.f,0.f,0.f},{0.f,0.f,0.f,0.f},{0.f,0.f,0.f,0.f},{0.f,0.f,0.f,0.f}};
  int n0 = blockIdx.x * 64;
  nt64_core(Gb0, 512, W2tb0 + (size_t)n0 * 512, 512, 16, acc);
  dw_epilogue256(acc, n0, V, b2in, wc2, Dwb_o, Dwt_o, b2out, smem);
}

// ================== stage bodies (shared by fallback kernels + cooperative kernel) ==================

// stage 1 job b: E slices (b<56) || W2 update (56<=b<448)
__device__ __forceinline__ void s1_body(
    int b,
    const ushort* __restrict__ Dwb, const ushort* __restrict__ Dwtb,
    const ushort* __restrict__ Gtb, const ushort* __restrict__ W2b_c,
    const float* __restrict__ W2c, float* __restrict__ W2n,
    ushort* __restrict__ W2b_n, ushort* __restrict__ W2tb_n,
    float* __restrict__ Esl) {
  f32x4 acc[4] = {{0.f,0.f,0.f,0.f},{0.f,0.f,0.f,0.f},{0.f,0.f,0.f,0.f},{0.f,0.f,0.f,0.f}};
  if (b < 56) {
    int s = b % 7, nt = b / 7;
    nt64_core(Dwb + s * 448, DM, W2b_c + (size_t)nt * 64 * DM + s * 448, DM, 14, acc);
    nt64_store(acc, Esl + (size_t)s * 32768 + nt * 64, 512);
  } else {
    int li = b - 56;
    int d0 = (li % 49) * 64, h0 = (li / 49) * 64;
    nt64_core(Gtb + (size_t)h0 * 64, 64, Dwtb + (size_t)d0 * 64, 64, 2, acc);
    int lane = threadIdx.x & 63, wvv = threadIdx.x >> 6;
    int r0 = (wvv >> 1) * 32 + ((lane >> 4) << 2);
    int c0 = (wvv & 1) * 32 + (lane & 15);
    #pragma unroll
    for (int r = 0; r < 4; ++r) {
      #pragma unroll
      for (int p = 0; p < 4; ++p) {
        int h = h0 + r0 + r + ((p >> 1) ? 16 : 0);
        int d = d0 + c0 + ((p & 1) ? 16 : 0);
        size_t off = (size_t)h * DM + d;
        float w = W2c[off] - acc[p][r];
        W2n[off] = w;
        ushort wb = f2bf(w);
        W2b_n[off] = wb;
        W2tb_n[(size_t)d * DH + h] = wb;
      }
    }
  }
}

// stage 2 job blk: G2 stripes (blk<32) || hsEw (32..39, ch<7) || hred inline (40..167, ch<7)
__device__ __forceinline__ void s2_body(
    int blk, int ch, float* smem,
    const float* __restrict__ KKf,
    const float* __restrict__ Esl, const float* __restrict__ GpC,
    const float* __restrict__ Hcur, const float* __restrict__ b1e,
    float* __restrict__ b1o, ushort* __restrict__ G2b, float* __restrict__ EwOut,
    const float* __restrict__ Hcorr, const float* __restrict__ Hbase_n,
    float* __restrict__ HhN, ushort* __restrict__ GbN,
    ushort* __restrict__ GtbN, float* __restrict__ GpN) {
  int tid = threadIdx.x;
  int tri = ch * (ch + 1) / 2;
  if (blk < 32) {
    float* KKs = smem;          // 64*65 = 4160
    float* Ews = smem + 4160;   // 1024
    float* b1l = smem + 5184;   // 16
    const float* KKcc = KKf + (size_t)(tri + ch) * 4096;
    int n0 = blk * 16;
    #pragma unroll
    for (int q = 0; q < 16; ++q) {
      int e = q * 256 + tid;
      KKs[(e >> 6) * 65 + (e & 63)] = KKcc[e];
    }
    #pragma unroll
    for (int q = 0; q < 4; ++q) {
      int e = q * 256 + tid;
      int i = e >> 4, cc = e & 15;
      size_t off = (size_t)i * 512 + n0 + cc;
      float s = 0.f;
      #pragma unroll
      for (int sl = 0; sl < 7; ++sl) s += Esl[(size_t)sl * 32768 + off];
      Ews[e] = s * GpC[off];
    }
    __syncthreads();
    if (tid < 16) {
      float s = 0.f;
      for (int i = 0; i < 64; ++i) s += Ews[i * 16 + tid];
      b1l[tid] = b1e[n0 + tid] - s;
    }
    __syncthreads();
    #pragma unroll
    for (int q = 0; q < 4; ++q) {
      int e = q * 256 + tid;
      int mrow = e >> 4, cc = e & 15;
      float corr = 0.f;
      #pragma unroll 16
      for (int i = 0; i < 64; ++i) corr += KKs[mrow * 65 + i] * Ews[i * 16 + cc];
      float xx = Hcur[(size_t)mrow * 512 + n0 + cc] - corr + b1l[cc];
      G2b[(size_t)mrow * 512 + n0 + cc] = f2bf(gelu_only(xx));
    }
  } else if (blk < 40) {
    float* Bs = smem;           // 4096 (Ew [k][c])
    int bx = blk - 32;
    int n0 = bx * 64;
    #pragma unroll
    for (int q = 0; q < 16; ++q) {
      int e = q * 256 + tid;
      int k = e >> 6, c = e & 63;
      size_t off = (size_t)k * 512 + n0 + c;
      float s = 0.f;
      #pragma unroll
      for (int sl = 0; sl < 7; ++sl) s += Esl[(size_t)sl * 32768 + off];
      float ew = s * GpC[off];
      Bs[k * 64 + c] = ew;
      EwOut[off] = ew;
    }
    __syncthreads();
    if (tid < 64) {
      float s = 0.f;
      for (int k = 0; k < 64; ++k) s += Bs[k * 64 + tid];
      b1o[n0 + tid] = b1e[n0 + tid] - s;
    }
  } else {
    // hred inline: self-contained 16x16 tile of H_{ch+1} -> next-chunk G state
    float* Ewt = smem;          // 1024
    float* KKs = smem + 1024;   // 16*65 = 1040
    float* b1l = smem + 2064;   // 16
    int bh = blk - 40;          // 0..127
    int m0 = (bh >> 5) * 16;
    int c0 = (bh & 31) * 16;
    #pragma unroll
    for (int q = 0; q < 4; ++q) {
      int e = q * 256 + tid;
      int i = e >> 4, cl = e & 15;
      size_t off = (size_t)i * 512 + c0 + cl;
      float s = 0.f;
      #pragma unroll
      for (int sl = 0; sl < 7; ++sl) s += Esl[(size_t)sl * 32768 + off];
      Ewt[i * 16 + cl] = s * GpC[off];
    }
    const float* KK = KKf + (size_t)((ch + 1) * (ch + 2) / 2 + ch) * 4096;
    #pragma unroll
    for (int q = 0; q < 4; ++q) {
      int e = q * 256 + tid;
      int ml = e >> 6, i = e & 63;
      KKs[ml * 65 + i] = KK[(m0 + ml) * 64 + i];
    }
    __syncthreads();
    if (tid < 16) {
      float s = 0.f;
      for (int i = 0; i < 64; ++i) s += Ewt[i * 16 + tid];
      b1l[tid] = b1e[c0 + tid] - s;
    }
    __syncthreads();
    int ml = tid >> 4, cl = tid & 15;
    int m = m0 + ml, c = c0 + cl;
    float corr = 0.f;
    #pragma unroll 16
    for (int i = 0; i < 64; ++i) corr += KKs[ml * 65 + i] * Ewt[i * 16 + cl];
    size_t off = (size_t)m * 512 + c;
    float s = Hbase_n[off] - corr;
    for (int j = 0; j < ch; ++j) s -= Hcorr[(size_t)j * 32768 + off];
    HhN[off] = s;
    float g, gp;
    gelu_both(s + b1l[cl], g, gp);
    GbN[off] = f2bf(g);
    GtbN[(size_t)c * 64 + m] = f2bf(g);
    GpN[off] = gp;
  }
}

// stage 3 job b: Y->out (b<49) || pred_{ch+1}->Dw+b2' (49..97, ch<7) || Hcorr ch+2 (rest, ch<6)
__device__ __forceinline__ void s3_body(
    int b, int ch, float* smem,
    const ushort* __restrict__ G2b, const ushort* __restrict__ W2tb,
    const float* __restrict__ b2n, float* __restrict__ out,
    const ushort* __restrict__ Gnb, const float* __restrict__ Vn, float wc2,
    float* __restrict__ b2out, ushort* __restrict__ Dwb, ushort* __restrict__ Dwtb,
    const float* __restrict__ KKf,
    const float* __restrict__ Ewst, float* __restrict__ Hcorr) {
  int t0 = ch * 64;
  if (b < 49) {
    f32x4 acc[4] = {{0.f,0.f,0.f,0.f},{0.f,0.f,0.f,0.f},{0.f,0.f,0.f,0.f},{0.f,0.f,0.f,0.f}};
    int n0 = b * 64;
    nt64_core(G2b, 512, W2tb + (size_t)n0 * 512, 512, 16, acc);
    int lane = threadIdx.x & 63, wvv = threadIdx.x >> 6;
    int r0 = (wvv >> 1) * 32 + ((lane >> 4) << 2);
    int c0 = (wvv & 1) * 32 + (lane & 15);
    #pragma unroll
    for (int r = 0; r < 4; ++r) {
      #pragma unroll
      for (int p = 0; p < 4; ++p) {
        int m = r0 + r + ((p >> 1) ? 16 : 0);
        int d = n0 + c0 + ((p & 1) ? 16 : 0);
        out[(size_t)(t0 + m) * DM + d] = acc[p][r] + b2n[d];
      }
    }
  } else if (ch < 7 && b < 98) {
    f32x4 acc[4] = {{0.f,0.f,0.f,0.f},{0.f,0.f,0.f,0.f},{0.f,0.f,0.f,0.f},{0.f,0.f,0.f,0.f}};
    int n0 = (b - 49) * 64;
    nt64_core(Gnb, 512, W2tb + (size_t)n0 * 512, 512, 16, acc);
    dw_epilogue256(acc, n0, Vn, b2n, wc2, Dwb, Dwtb, b2out, smem);
  } else {
    int j2 = b - (ch < 7 ? 98 : 49);
    int j = j2 >> 3, bx = j2 & 7;      // j <= ch, corrections for chunk ch+2
    int trin = (ch + 2) * (ch + 3) / 2;
    hs_corr_job(KKf + (size_t)(trin + j) * 4096, Ewst + (size_t)j * 32768,
                Hcorr + (size_t)j * 32768, bx, smem);
  }
}

// ================== fallback per-stage kernels (R7 path) ==================
__global__ __launch_bounds__(256) void p4w2_kernel(
    const ushort* __restrict__ Dwb, const ushort* __restrict__ Dwtb,
    const ushort* __restrict__ Gtb, const ushort* __restrict__ W2b_c,
    const float* __restrict__ W2c, float* __restrict__ W2n,
    ushort* __restrict__ W2b_n, ushort* __restrict__ W2tb_n,
    float* __restrict__ Esl) {
  s1_body(blockIdx.x, Dwb, Dwtb, Gtb, W2b_c, W2c, W2n, W2b_n, W2tb_n, Esl);
}

__global__ __launch_bounds__(256) void g2hr_kernel(
    const float* __restrict__ KKf, int ch,
    const float* __restrict__ Esl, const float* __restrict__ GpC,
    const float* __restrict__ Hcur, const float* __restrict__ b1e,
    float* __restrict__ b1o, ushort* __restrict__ G2b, float* __restrict__ EwOut,
    const float* __restrict__ Hcorr, const float* __restrict__ Hbase_n,
    float* __restrict__ HhN, ushort* __restrict__ GbN,
    ushort* __restrict__ GtbN, float* __restrict__ GpN) {
  __shared__ float smem[8192];
  s2_body(blockIdx.x, ch, smem, KKf, Esl, GpC, Hcur, b1e, b1o, G2b, EwOut,
          Hcorr, Hbase_n, HhN, GbN, GtbN, GpN);
}

__global__ __launch_bounds__(256) void yp3_kernel(
    const ushort* __restrict__ G2b, const ushort* __restrict__ W2tb,
    const float* __restrict__ b2n, float* __restrict__ out, int ch,
    const ushort* __restrict__ Gnb, const float* __restrict__ Vn, float wc2,
    float* __restrict__ b2out, ushort* __restrict__ Dwb, ushort* __restrict__ Dwtb,
    const float* __restrict__ KKf,
    const float* __restrict__ Ewst, float* __restrict__ Hcorr) {
  __shared__ float smem[8192];
  s3_body(blockIdx.x, ch, smem, G2b, W2tb, b2n, out, Gnb, Vn, wc2,
          b2out, Dwb, Dwtb, KKf, Ewst, Hcorr);
}

// ================== cooperative persistent chunk-loop kernel ==================
struct CLP {
  const float* KKf;
  float* Esl;
  const float* Hbase;
  float* Hcorr;
  float* Ewst;
  float* out;
  const float* nv;
  float* HhA; float* HhB;
  float* GpA; float* GpB;
  ushort* GbA; ushort* GbB;
  ushort* GtbA; ushort* GtbB;
  ushort* G2b;
  ushort* Dwb; ushort* Dwtb;
  float* W2A; float* W2B;
  ushort* W2bA; ushort* W2bB;
  ushort* W2tbA; ushort* W2tbB;
  const float* W2_0; const ushort* W2b0c; const ushort* W2tb0c;
  const float* b1_0; float* b1A; float* b1B;
  float* b2A; float* b2B;
  float wc2;
};

__global__ __launch_bounds__(256, 2) void chunk_kernel(CLP p) {
  cooperative_groups::grid_group grid = cooperative_groups::this_grid();
  __shared__ float smem[8192];
  int G = gridDim.x;
  for (int ch = 0; ch < 8; ++ch) {
    const float* b1e = ch ? (((ch - 1) & 1) ? p.b1B : p.b1A) : p.b1_0;
    const float* W2c = ch ? (((ch - 1) & 1) ? p.W2B : p.W2A) : p.W2_0;
    const ushort* W2b_c = ch ? (((ch - 1) & 1) ? p.W2bB : p.W2bA) : p.W2b0c;
    const ushort* Gtb_c = (ch & 1) ? p.GtbB : p.GtbA;
    float* W2n = (ch & 1) ? p.W2B : p.W2A;
    ushort* W2b_n = (ch & 1) ? p.W2bB : p.W2bA;
    ushort* W2tb_n = (ch & 1) ? p.W2tbB : p.W2tbA;

    // ---- stage 1 ----
    for (int j = blockIdx.x; j < 448; j += G) {
      s1_body(j, p.Dwb, p.Dwtb, Gtb_c, W2b_c, W2c, W2n, W2b_n, W2tb_n, p.Esl);
      __syncthreads();
    }
    grid.sync();

    // ---- stage 2 ----
    const float* GpC = (ch & 1) ? p.GpB : p.GpA;
    const float* Hcur = (ch & 1) ? p.HhB : p.HhA;
    float* b1o = (ch & 1) ? p.b1B : p.b1A;
    float* HhN = ((ch + 1) & 1) ? p.HhB : p.HhA;
    ushort* GbN = ((ch + 1) & 1) ? p.GbB : p.GbA;
    ushort* GtbN = ((ch + 1) & 1) ? p.GtbB : p.GtbA;
    float* GpN = ((ch + 1) & 1) ? p.GpB : p.GpA;
    int n2 = (ch < 7) ? 168 : 32;
    for (int j = blockIdx.x; j < n2; j += G) {
      s2_body(j, ch, smem, p.KKf, p.Esl, GpC, Hcur, b1e, b1o, p.G2b,
              p.Ewst + (size_t)ch * 32768, p.Hcorr,
              p.Hbase + (size_t)((ch + 1) & 7) * 32768, HhN, GbN, GtbN, GpN);
      __syncthreads();
    }
    grid.sync();

    // ---- stage 3 ----
    const ushort* W2tb_cur = (ch & 1) ? p.W2tbB : p.W2tbA;
    const float* b2n = (ch & 1) ? p.b2B : p.b2A;
    const ushort* Gnb = ((ch + 1) & 1) ? p.GbB : p.GbA;
    float* b2out = ((ch + 1) & 1) ? p.b2B : p.b2A;
    int g3 = 49 + (ch < 7 ? 49 : 0) + (ch < 6 ? 8 * (ch + 1) : 0);
    for (int j = blockIdx.x; j < g3; j += G) {
      s3_body(j, ch, smem, p.G2b, W2tb_cur, b2n, p.out,
              Gnb, p.nv + (size_t)((ch + 1) & 7) * 200704, p.wc2,
              b2out, p.Dwb, p.Dwtb, p.KKf, p.Ewst, p.Hcorr);
      __syncthreads();
    }
    if (ch < 7) grid.sync();
  }
}

extern "C" void kernel_launch(void* const* d_in, const int* in_sizes, int n_in,
                              void* d_out, int out_size, void* d_ws, size_t ws_size,
                              hipStream_t stream) {
  const float* x  = (const float*)d_in[0];
  const float* wk = (const float*)d_in[1];
  const float* bk = (const float*)d_in[2];
  const float* wv = (const float*)d_in[3];
  const float* bv = (const float*)d_in[4];
  const float* sk = (const float*)d_in[5];
  const float* sv = (const float*)d_in[6];
  const float* W1 = (const float*)d_in[7];
  const float* b1 = (const float*)d_in[8];
  const float* W2 = (const float*)d_in[9];
  const float* b2 = (const float*)d_in[10];
  float* out = (float*)d_out;
  float* ws  = (float*)d_ws;

  // workspace layout (float units) — identical to R7
  ushort* nkb   = (ushort*)ws;                       // 802816 f
  ushort* w1tb  = (ushort*)(ws + 802816);            // 802816 f
  float* nv     = ws + 1605632;                      // 1605632
  float* W2A    = nv + 1605632;                      // 1605632
  float* W2B    = W2A + 1605632;                     // 1605632
  float* bf_base = W2B + 1605632;
  ushort* W2b0  = (ushort*)bf_base;                  // 802816 f
  ushort* W2tb0 = (ushort*)(bf_base + 802816);       // 802816 f
  ushort* W2bA  = (ushort*)(bf_base + 1605632);      // 802816 f
  ushort* W2bB  = (ushort*)(bf_base + 2408448);      // 802816 f
  ushort* W2tbA = (ushort*)(bf_base + 3211264);      // 802816 f
  ushort* W2tbB = (ushort*)(bf_base + 4014080);      // 802816 f
  float* Esl    = bf_base + 4816896;                 // 229376 (7 x 32768)
  float* Hb_sl  = Esl + 229376;                      // 1835008 (7 x 262144)
  float* KKsl   = Hb_sl + 1835008;                   // 1032192 (36 x 7 x 4096)
  float* Hbase  = KKsl + 1032192;                    // 262144
  float* KKf    = Hbase + 262144;                    // 147456
  float* HhA    = KKf + 147456;                      // 32768
  float* HhB    = HhA + 32768;                       // 32768
  float* GpA    = HhB + 32768;                       // 32768
  float* GpB    = GpA + 32768;                       // 32768
  ushort* GbA   = (ushort*)(GpB + 32768);            // 16384 f
  ushort* GbB   = (ushort*)(GpB + 49152);            // 16384 f
  ushort* GtbA  = (ushort*)(GpB + 65536);            // 16384 f
  ushort* GtbB  = (ushort*)(GpB + 81920);            // 16384 f
  ushort* G2b   = (ushort*)(GpB + 98304);            // 16384 f
  ushort* Dwb   = (ushort*)(GpB + 114688);           // 100352 f
  ushort* Dwtb  = (ushort*)(GpB + 215040);           // 100352 f
  float* Ewst   = GpB + 315392;                      // 262144 (8 x 32768)
  float* Hcorr  = Ewst + 262144;                     // 229376 (7 x 32768)
  float* b1A    = Hcorr + 229376;                    // 512
  float* b1B    = b1A + 512;                         // 512
  float* b2A    = b1B + 512;                         // 3136
  float* b2B    = b2A + 3136;                        // 3136

  float* W2buf[2]   = { W2A, W2B };
  ushort* W2bb[2]   = { W2bA, W2bB };
  ushort* W2tbb[2]  = { W2tbA, W2tbB };
  ushort* Gbb[2]    = { GbA, GbB };
  ushort* Gtbb[2]   = { GtbA, GtbB };
  float* Hhb[2]     = { HhA, HhB };
  float* Gpb[2]     = { GpA, GpB };
  float* b1buf[2]   = { b1A, b1B };
  float* b2buf[2]   = { b2A, b2B };

  // weights[i] = ETA0 * ALPHA^i * (ALPHA^63 / ALPHA^i) = ETA0 * ALPHA^63 (constant)
  float wc2 = 2.0f * (float)(0.1 * pow(0.9, 63.0));

  conv_rms<<<2352, 256, 0, stream>>>(x, wk, bk, wv, bv, sk, sv,
                                     W1, w1tb, W2, W2b0, W2tb0, nkb, nv);
  u1_kernel<<<700, 256, 0, stream>>>(nkb, w1tb, KKsl, Hb_sl);
  u2_kernel<<<1600, 256, 0, stream>>>(KKsl, Hb_sl, KKf, Hbase, b1, HhA, GbA, GtbA, GpA);
  pred0_kernel<<<49, 256, 0, stream>>>(GbA, W2tb0, nv, b2, wc2, b2A, Dwb, Dwtb);

  // cooperative persistent chunk loop
  CLP cp;
  cp.KKf = KKf; cp.Esl = Esl; cp.Hbase = Hbase; cp.Hcorr = Hcorr; cp.Ewst = Ewst;
  cp.out = out; cp.nv = nv;
  cp.HhA = HhA; cp.HhB = HhB; cp.GpA = GpA; cp.GpB = GpB;
  cp.GbA = GbA; cp.GbB = GbB; cp.GtbA = GtbA; cp.GtbB = GtbB;
  cp.G2b = G2b; cp.Dwb = Dwb; cp.Dwtb = Dwtb;
  cp.W2A = W2A; cp.W2B = W2B; cp.W2bA = W2bA; cp.W2bB = W2bB;
  cp.W2tbA = W2tbA; cp.W2tbB = W2tbB;
  cp.W2_0 = W2; cp.W2b0c = W2b0; cp.W2tb0c = W2tb0;
  cp.b1_0 = b1; cp.b1A = b1A; cp.b1B = b1B;
  cp.b2A = b2A; cp.b2B = b2B;
  cp.wc2 = wc2;

  int maxPerCU = 0;
  if (hipOccupancyMaxActiveBlocksPerMultiprocessor(&maxPerCU, chunk_kernel, 256, 0)
        != hipSuccess || maxPerCU < 1)
    maxPerCU = 1;
  int coopGrid = maxPerCU * 256;
  if (coopGrid > 448) coopGrid = 448;

  void* kargs[] = { &cp };
  hipError_t cerr = hipLaunchCooperativeKernel(chunk_kernel, dim3(coopGrid), dim3(256),
                                               kargs, 0, stream);
  if (cerr != hipSuccess) {
    // fallback: R7 3-kernel-per-chunk path (identical math via shared bodies)
    for (int ch = 0; ch < 8; ++ch) {
      const float* b1e  = ch ? b1buf[(ch - 1) & 1] : b1;
      const float* W2c  = ch ? W2buf[(ch - 1) & 1] : W2;
      const ushort* W2b_c = ch ? W2bb[(ch - 1) & 1] : W2b0;

      p4w2_kernel<<<448, 256, 0, stream>>>(
          Dwb, Dwtb, Gtbb[ch & 1], W2b_c, W2c,
          W2buf[ch & 1], W2bb[ch & 1], W2tbb[ch & 1], Esl);
      g2hr_kernel<<<(ch < 7 ? 168 : 32), 256, 0, stream>>>(
          KKf, ch, Esl, Gpb[ch & 1], Hhb[ch & 1], b1e, b1buf[ch & 1],
          G2b, Ewst + (size_t)ch * 32768,
          Hcorr, Hbase + (size_t)((ch + 1) & 7) * 32768,
          Hhb[(ch + 1) & 1], Gbb[(ch + 1) & 1], Gtbb[(ch + 1) & 1], Gpb[(ch + 1) & 1]);
      int g3 = 49 + (ch < 7 ? 49 : 0) + (ch < 6 ? 8 * (ch + 1) : 0);
      yp3_kernel<<<g3, 256, 0, stream>>>(
          G2b, W2tbb[ch & 1], b2buf[ch & 1], out, ch,
          Gbb[(ch + 1) & 1], nv + (size_t)((ch + 1) & 7) * 200704, wc2,
          b2buf[(ch + 1) & 1], Dwb, Dwtb,
          KKf, Ewst, Hcorr);
    }
  }
}

// Round 9
// 349.963 us; speedup vs baseline: 3.5051x; 3.5051x over previous
//
#include <hip/hip_runtime.h>
#include <math.h>

#define DM 3136
#define DH 512

typedef __attribute__((ext_vector_type(8))) short bf16x8;
typedef __attribute__((ext_vector_type(4))) float f32x4;

__device__ __forceinline__ ushort f2bf(float f) {
  union { float f; unsigned u; } v; v.f = f;
  unsigned r = v.u + 0x7FFFu + ((v.u >> 16) & 1u);
  return (ushort)(r >> 16);
}
__device__ __forceinline__ float bf2f(ushort u) {
  union { float f; unsigned u; } v; v.u = ((unsigned)u) << 16;
  return v.f;
}

#define MICRO_4x4 \
    acc[0][0] += a.x*b.x; acc[0][1] += a.x*b.y; acc[0][2] += a.x*b.z; acc[0][3] += a.x*b.w; \
    acc[1][0] += a.y*b.x; acc[1][1] += a.y*b.y; acc[1][2] += a.y*b.z; acc[1][3] += a.y*b.w; \
    acc[2][0] += a.z*b.x; acc[2][1] += a.z*b.y; acc[2][2] += a.z*b.z; acc[2][3] += a.z*b.w; \
    acc[3][0] += a.w*b.x; acc[3][1] += a.w*b.y; acc[3][2] += a.w*b.z; acc[3][3] += a.w*b.w;

// ---------------- gelu ----------------
__device__ __forceinline__ void gelu_both(float xx, float& g, float& gp) {
  const float c = 0.7978845608028654f;
  const float a = 0.044715f;
  float x2 = xx * xx;
  float u = c * (xx + a * xx * x2);
  float t = tanhf(u);
  g  = 0.5f * xx * (1.f + t);
  gp = 0.5f * (1.f + t) + 0.5f * xx * (1.f - t * t) * c * (1.f + 3.f * a * x2);
}
__device__ __forceinline__ float gelu_only(float xx) {
  const float c = 0.7978845608028654f;
  const float a = 0.044715f;
  float u = c * (xx + a * xx * xx * xx);
  return 0.5f * xx * (1.f + tanhf(u));
}

// ---------------- nt64 MFMA core: C[i,j] += sum_k A[i,k]*B[j,k] ----------------
__device__ __forceinline__ void nt64_core(
    const ushort* __restrict__ A, int lda,
    const ushort* __restrict__ B, int ldb,
    int ksteps, f32x4* acc) {
  int lane = threadIdx.x & 63;
  int wv = threadIdx.x >> 6;
  int qr = wv >> 1, qc = wv & 1;
  int lr = lane & 15;
  int lk = (lane >> 4) << 3;
  const ushort* pa0 = A + (size_t)(qr * 32 + lr) * lda + lk;
  const ushort* pa1 = pa0 + (size_t)16 * lda;
  const ushort* pb0 = B + (size_t)(qc * 32 + lr) * ldb + lk;
  const ushort* pb1 = pb0 + (size_t)16 * ldb;
  bf16x8 a0 = *(const bf16x8*)pa0;
  bf16x8 a1 = *(const bf16x8*)pa1;
  bf16x8 b0 = *(const bf16x8*)pb0;
  bf16x8 b1 = *(const bf16x8*)pb1;
  for (int s = 0; s < ksteps; ++s) {
    int sn = (s + 1 < ksteps) ? (s + 1) * 32 : s * 32;
    bf16x8 na0 = *(const bf16x8*)(pa0 + sn);
    bf16x8 na1 = *(const bf16x8*)(pa1 + sn);
    bf16x8 nb0 = *(const bf16x8*)(pb0 + sn);
    bf16x8 nb1 = *(const bf16x8*)(pb1 + sn);
    acc[0] = __builtin_amdgcn_mfma_f32_16x16x32_bf16(a0, b0, acc[0], 0, 0, 0);
    acc[1] = __builtin_amdgcn_mfma_f32_16x16x32_bf16(a0, b1, acc[1], 0, 0, 0);
    acc[2] = __builtin_amdgcn_mfma_f32_16x16x32_bf16(a1, b0, acc[2], 0, 0, 0);
    acc[3] = __builtin_amdgcn_mfma_f32_16x16x32_bf16(a1, b1, acc[3], 0, 0, 0);
    a0 = na0; a1 = na1; b0 = nb0; b1 = nb1;
  }
}

__device__ __forceinline__ void nt64_store(const f32x4* acc, float* __restrict__ dst, int ldc) {
  int lane = threadIdx.x & 63, wv = threadIdx.x >> 6;
  int r0 = (wv >> 1) * 32 + ((lane >> 4) << 2);
  int c0 = (wv & 1) * 32 + (lane & 15);
  #pragma unroll
  for (int r = 0; r < 4; ++r) {
    dst[(size_t)(r0 + r) * ldc + c0]           = acc[0][r];
    dst[(size_t)(r0 + r) * ldc + c0 + 16]      = acc[1][r];
    dst[(size_t)(r0 + r + 16) * ldc + c0]      = acc[2][r];
    dst[(size_t)(r0 + r + 16) * ldc + c0 + 16] = acc[3][r];
  }
}

// Dw epilogue (256-thr, R4-proven): dw = wc2*(acc + b2in - V);
// bf16 both layouts + b2out = b2in - colsum
__device__ __forceinline__ void dw_epilogue256(
    const f32x4* acc, int n0, const float* __restrict__ Vn,
    const float* __restrict__ b2in, float wc2,
    ushort* __restrict__ Dwb_o, ushort* __restrict__ Dwt_o,
    float* __restrict__ b2out, float* smem) {
  int lane = threadIdx.x & 63, wvv = threadIdx.x >> 6;
  int qr = wvv >> 1, qc = wvv & 1;
  int r0 = qr * 32 + ((lane >> 4) << 2);
  int c0 = qc * 32 + (lane & 15);
  float csum[2] = {0.f, 0.f};
  #pragma unroll
  for (int r = 0; r < 4; ++r) {
    #pragma unroll
    for (int p = 0; p < 4; ++p) {
      int m = r0 + r + ((p >> 1) ? 16 : 0);
      int dl = c0 + ((p & 1) ? 16 : 0);
      int d = n0 + dl;
      float dw = wc2 * (acc[p][r] + b2in[d] - Vn[(size_t)m * DM + d]);
      ushort db = f2bf(dw);
      Dwb_o[(size_t)m * DM + d] = db;
      Dwt_o[(size_t)d * 64 + m] = db;
      csum[p & 1] += dw;
    }
  }
  int slot = qr * 4 + ((lane >> 4) & 3);
  smem[(size_t)c0 * 8 + slot] = csum[0];
  smem[(size_t)(c0 + 16) * 8 + slot] = csum[1];
  __syncthreads();
  if (threadIdx.x < 64) {
    float s = 0.f;
    #pragma unroll
    for (int q = 0; q < 8; ++q) s += smem[threadIdx.x * 8 + q];
    b2out[n0 + threadIdx.x] = b2in[n0 + threadIdx.x] - s;
  }
}

// ---------------- conv3x3 + RMSNorm + W1/W2 bf16 prep tails ----------------
__global__ __launch_bounds__(256) void conv_rms(
    const float* __restrict__ x,
    const float* __restrict__ wk, const float* __restrict__ bk,
    const float* __restrict__ wv, const float* __restrict__ bv,
    const float* __restrict__ sk, const float* __restrict__ sv,
    const float* __restrict__ W1, ushort* __restrict__ w1tb,
    const float* __restrict__ W2, ushort* __restrict__ W2b0, ushort* __restrict__ W2tb0,
    ushort* __restrict__ nkb, float* __restrict__ nv) {
  __shared__ float smem[4160];
  int tid = threadIdx.x;
  if (blockIdx.x >= 1960) {
    int t = blockIdx.x - 1960;           // 0..391
    int d0 = (t % 49) * 64, h0 = (t / 49) * 64;
    int c = tid & 63, rq = tid >> 6;
    #pragma unroll
    for (int q = 0; q < 16; ++q) {
      int r = q * 4 + rq;
      float v = W2[(size_t)(h0 + r) * DM + d0 + c];
      smem[r * 65 + c] = v;
      W2b0[(size_t)(h0 + r) * DM + d0 + c] = f2bf(v);
    }
    __syncthreads();
    #pragma unroll
    for (int q = 0; q < 16; ++q) {
      int r = q * 4 + rq;
      W2tb0[(size_t)(d0 + r) * DH + h0 + c] = f2bf(smem[c * 65 + r]);
    }
    return;
  }
  if (blockIdx.x >= 1568) {
    int t = blockIdx.x - 1568;           // 0..391
    int d0 = (t % 49) * 64, h0 = (t / 49) * 64;
    int c = tid & 63, rq = tid >> 6;
    #pragma unroll
    for (int q = 0; q < 16; ++q) {
      int r = q * 4 + rq;
      smem[r * 65 + c] = W1[(size_t)(d0 + r) * 512 + h0 + c];
    }
    __syncthreads();
    #pragma unroll
    for (int q = 0; q < 16; ++q) {
      int r = q * 4 + rq;
      w1tb[(size_t)(h0 + r) * 3136 + d0 + c] = f2bf(smem[c * 65 + r]);
    }
    return;
  }
  float* swk = smem;
  float* swv = smem + 144;
  float* sb  = smem + 288;
  if (tid < 144) { swk[tid] = wk[tid]; swv[tid] = wv[tid]; }
  if (tid < 4) {
    sb[tid] = bk[tid]; sb[4 + tid] = bv[tid];
    sb[8 + tid] = sk[tid]; sb[12 + tid] = sv[tid];
  }
  __syncthreads();
  int idx = blockIdx.x * 256 + tid;
  int t = idx / 784, hw = idx - t * 784;
  int h = hw / 28, w = hw - h * 28;
  float ak[4], av[4];
  #pragma unroll
  for (int c = 0; c < 4; ++c) { ak[c] = sb[c]; av[c] = sb[4 + c]; }
  const float* xt = x + (size_t)t * DM;
  for (int kh = 0; kh < 3; ++kh) {
    int ih = h + kh - 1;
    if (ih < 0 || ih >= 28) continue;
    for (int kw = 0; kw < 3; ++kw) {
      int iw = w + kw - 1;
      if (iw < 0 || iw >= 28) continue;
      int base = (kh * 3 + kw) * 16;
      #pragma unroll
      for (int ci = 0; ci < 4; ++ci) {
        float xv = xt[ci * 784 + ih * 28 + iw];
        #pragma unroll
        for (int co = 0; co < 4; ++co) {
          ak[co] += xv * swk[base + ci * 4 + co];
          av[co] += xv * swv[base + ci * 4 + co];
        }
      }
    }
  }
  float mk = (ak[0]*ak[0] + ak[1]*ak[1] + ak[2]*ak[2] + ak[3]*ak[3]) * 0.25f + 1e-6f;
  float mv = (av[0]*av[0] + av[1]*av[1] + av[2]*av[2] + av[3]*av[3]) * 0.25f + 1e-6f;
  float ik = 1.f / sqrtf(mk), iv = 1.f / sqrtf(mv);
  ushort4 ok = { f2bf(ak[0]*ik*sb[8]), f2bf(ak[1]*ik*sb[9]),
                 f2bf(ak[2]*ik*sb[10]), f2bf(ak[3]*ik*sb[11]) };
  float4 ov = { av[0]*iv*sb[12], av[1]*iv*sb[13], av[2]*iv*sb[14], av[3]*iv*sb[15] };
  *(ushort4*)&nkb[(size_t)idx * 4] = ok;
  *(float4*)&nv[(size_t)idx * 4] = ov;
}

// ---------------- u1: KK + Hb slices (bf16 MFMA NT) ----------------
__global__ __launch_bounds__(256) void u1_kernel(
    const ushort* __restrict__ nkb, const ushort* __restrict__ w1tb,
    float* __restrict__ KKsl, float* __restrict__ Hb_sl) {
  f32x4 acc[4] = {{0.f,0.f,0.f,0.f},{0.f,0.f,0.f,0.f},{0.f,0.f,0.f,0.f},{0.f,0.f,0.f,0.f}};
  int job = blockIdx.x;
  if (job < 448) {
    int s = job % 7;
    int t = job / 7;
    int m0 = (t >> 3) * 64, n0 = (t & 7) * 64;
    nt64_core(nkb + (size_t)m0 * DM + s * 448, DM, w1tb + (size_t)n0 * DM + s * 448, DM, 14, acc);
    nt64_store(acc, Hb_sl + (size_t)s * 262144 + (size_t)m0 * 512 + n0, 512);
  } else {
    int j2 = job - 448;
    int p = j2 / 7, s = j2 % 7;
    int c = 0;
    while ((c + 1) * (c + 2) / 2 <= p) ++c;
    int j = p - c * (c + 1) / 2;
    nt64_core(nkb + (size_t)c * 64 * DM + s * 448, DM, nkb + (size_t)j * 64 * DM + s * 448, DM, 14, acc);
    nt64_store(acc, KKsl + ((size_t)p * 7 + s) * 4096, 64);
  }
}

// u2: KKf (sum 7) + Hbase (sum 7) + fused hred for chunk 0
__global__ __launch_bounds__(256) void u2_kernel(
    const float* __restrict__ KKsl, const float* __restrict__ Hb_sl,
    float* __restrict__ KKf, float* __restrict__ Hbase,
    const float* __restrict__ b1,
    float* __restrict__ Hh, ushort* __restrict__ Gb, ushort* __restrict__ Gtb,
    float* __restrict__ Gp) {
  int i = blockIdx.x * 256 + threadIdx.x;
  if (i < 147456) {
    int pair = i >> 12, e = i & 4095;
    float s = 0.f;
    #pragma unroll
    for (int t = 0; t < 7; ++t) s += KKsl[((size_t)pair * 7 + t) * 4096 + e];
    KKf[i] = s;
  } else {
    int j = i - 147456;   // < 262144
    float s = 0.f;
    #pragma unroll
    for (int t = 0; t < 7; ++t) s += Hb_sl[(size_t)t * 262144 + j];
    Hbase[j] = s;
    if (j < 32768) {
      Hh[j] = s;
      float g, gp;
      gelu_both(s + b1[j & 511], g, gp);
      Gb[j] = f2bf(g);
      Gtb[(j & 511) * 64 + (j >> 9)] = f2bf(g);
      Gp[j] = gp;
    }
  }
}

// ---------------- hs_corr (fp32, for pipelined future Hcorr) ----------------
__device__ __forceinline__ void hs_corr_job(
    const float* __restrict__ KK, const float* __restrict__ Ewj,
    float* __restrict__ dst, int bx, float* smem) {
  float* As = smem;
  float* Bs = smem + 4096;
  int tid = threadIdx.x;
  int n0 = bx * 64;
  {
    int m = tid >> 2, ib = (tid & 3) * 16;
    #pragma unroll
    for (int q = 0; q < 4; ++q) {
      float4 v = *(const float4*)(KK + m * 64 + ib + q * 4);
      As[(ib + q*4 + 0)*64 + m] = v.x;
      As[(ib + q*4 + 1)*64 + m] = v.y;
      As[(ib + q*4 + 2)*64 + m] = v.z;
      As[(ib + q*4 + 3)*64 + m] = v.w;
    }
    int kr = tid >> 4, nn = (tid & 15) * 4;
    #pragma unroll
    for (int q = 0; q < 4; ++q)
      *(float4*)&Bs[(kr + q*16)*64 + nn] = *(const float4*)(Ewj + (size_t)(kr + q*16) * DH + n0 + nn);
  }
  __syncthreads();
  int tx = tid & 15, ty = tid >> 4;
  float acc[4][4] = {{0.f}};
  #pragma unroll 16
  for (int kk = 0; kk < 64; ++kk) {
    float4 a = *(const float4*)&As[kk*64 + ty * 4];
    float4 b = *(const float4*)&Bs[kk*64 + tx * 4];
    MICRO_4x4
  }
  #pragma unroll
  for (int r = 0; r < 4; ++r) {
    float4 v = { acc[r][0], acc[r][1], acc[r][2], acc[r][3] };
    *(float4*)&dst[(ty*4 + r) * DH + n0 + tx*4] = v;
  }
}

// ---------------- pred0: chunk-0 prediction -> Dw_0 + b2_0 ----------------
__global__ __launch_bounds__(256) void pred0_kernel(
    const ushort* __restrict__ Gb0, const ushort* __restrict__ W2tb0,
    const float* __restrict__ V, const float* __restrict__ b2in, float wc2,
    float* __restrict__ b2out, ushort* __restrict__ Dwb_o, ushort* __restrict__ Dwt_o) {
  __shared__ float smem[512];
  f32x4 acc[4] = {{0.f,0.f,0.f,0.f},{0.f,0.f,0.f,0.f},{0.f,0.f,0.f,0.f},{0.f,0.f,0.f,0.f}};
  int n0 = blockIdx.x * 64;
  nt64_core(Gb0, 512, W2tb0 + (size_t)n0 * 512, 512, 16, acc);
  dw_epilogue256(acc, n0, V, b2in, wc2, Dwb_o, Dwt_o, b2out, smem);
}

// ========== stage 1: E slices (56, MFMA) || W2 update (392, MFMA K=64, bf16 master) ==========
__global__ __launch_bounds__(256) void p4w2_kernel(
    const ushort* __restrict__ Dwb, const ushort* __restrict__ Dwtb,
    const ushort* __restrict__ Gtb, const ushort* __restrict__ W2b_c,
    ushort* __restrict__ W2b_n, ushort* __restrict__ W2tb_n,
    float* __restrict__ Esl) {
  f32x4 acc[4] = {{0.f,0.f,0.f,0.f},{0.f,0.f,0.f,0.f},{0.f,0.f,0.f,0.f},{0.f,0.f,0.f,0.f}};
  int b = blockIdx.x;
  if (b < 56) {
    int s = b % 7, nt = b / 7;
    nt64_core(Dwb + s * 448, DM, W2b_c + (size_t)nt * 64 * DM + s * 448, DM, 14, acc);
    nt64_store(acc, Esl + (size_t)s * 32768 + nt * 64, 512);
  } else {
    // W2n[h,d] = bf16( bf2f(W2b_c[h,d]) - sum_m G[m,h]*Dw[m,d] )
    int li = b - 56;
    int d0 = (li % 49) * 64, h0 = (li / 49) * 64;
    nt64_core(Gtb + (size_t)h0 * 64, 64, Dwtb + (size_t)d0 * 64, 64, 2, acc);
    int lane = threadIdx.x & 63, wvv = threadIdx.x >> 6;
    int r0 = (wvv >> 1) * 32 + ((lane >> 4) << 2);
    int c0 = (wvv & 1) * 32 + (lane & 15);
    #pragma unroll
    for (int r = 0; r < 4; ++r) {
      #pragma unroll
      for (int p = 0; p < 4; ++p) {
        int h = h0 + r0 + r + ((p >> 1) ? 16 : 0);
        int d = d0 + c0 + ((p & 1) ? 16 : 0);
        size_t off = (size_t)h * DM + d;
        float w = bf2f(W2b_c[off]) - acc[p][r];
        ushort wb = f2bf(w);
        W2b_n[off] = wb;
        W2tb_n[(size_t)d * DH + h] = wb;
      }
    }
  }
}

// ========== stage 2: G2 stripes (32) || hsEw Ew+b1' (8, ch<7) || hred inline (128, ch<7) ==========
__global__ __launch_bounds__(256) void g2hr_kernel(
    const float* __restrict__ KKf, int ch,
    const float* __restrict__ Esl, const float* __restrict__ GpC,
    const float* __restrict__ Hcur, const float* __restrict__ b1e,
    float* __restrict__ b1o, ushort* __restrict__ G2b, float* __restrict__ EwOut,
    const float* __restrict__ Hcorr, const float* __restrict__ Hbase_n,
    float* __restrict__ HhN, ushort* __restrict__ GbN,
    ushort* __restrict__ GtbN, float* __restrict__ GpN) {
  __shared__ float smem[5200];
  int blk = blockIdx.x;
  int tid = threadIdx.x;
  int tri = ch * (ch + 1) / 2;
  if (blk < 32) {
    // G2 tile: inline Ew (16 cols), local b1', corrected gelu. KKs padded stride 65.
    float* KKs = smem;          // 64*65 = 4160
    float* Ews = smem + 4160;   // 1024
    float* b1l = smem + 5184;   // 16
    const float* KKcc = KKf + (size_t)(tri + ch) * 4096;
    int n0 = blk * 16;
    #pragma unroll
    for (int q = 0; q < 16; ++q) {
      int e = q * 256 + tid;
      KKs[(e >> 6) * 65 + (e & 63)] = KKcc[e];
    }
    #pragma unroll
    for (int q = 0; q < 4; ++q) {
      int e = q * 256 + tid;
      int i = e >> 4, cc = e & 15;
      size_t off = (size_t)i * 512 + n0 + cc;
      float s = 0.f;
      #pragma unroll
      for (int sl = 0; sl < 7; ++sl) s += Esl[(size_t)sl * 32768 + off];
      Ews[e] = s * GpC[off];
    }
    __syncthreads();
    if (tid < 16) {
      float s = 0.f;
      for (int i = 0; i < 64; ++i) s += Ews[i * 16 + tid];
      b1l[tid] = b1e[n0 + tid] - s;
    }
    __syncthreads();
    #pragma unroll
    for (int q = 0; q < 4; ++q) {
      int e = q * 256 + tid;
      int mrow = e >> 4, cc = e & 15;
      float corr = 0.f;
      #pragma unroll 16
      for (int i = 0; i < 64; ++i) corr += KKs[mrow * 65 + i] * Ews[i * 16 + cc];
      float xx = Hcur[(size_t)mrow * 512 + n0 + cc] - corr + b1l[cc];
      G2b[(size_t)mrow * 512 + n0 + cc] = f2bf(gelu_only(xx));
    }
  } else if (blk < 40) {
    // hsEw: full Ew tile (64 cols) -> Ewst + b1o persistent
    float* Bs = smem;           // 4096 (Ew [k][c])
    int bx = blk - 32;
    int n0 = bx * 64;
    #pragma unroll
    for (int q = 0; q < 16; ++q) {
      int e = q * 256 + tid;
      int k = e >> 6, c = e & 63;
      size_t off = (size_t)k * 512 + n0 + c;
      float s = 0.f;
      #pragma unroll
      for (int sl = 0; sl < 7; ++sl) s += Esl[(size_t)sl * 32768 + off];
      float ew = s * GpC[off];
      Bs[k * 64 + c] = ew;
      EwOut[off] = ew;
    }
    __syncthreads();
    if (tid < 64) {
      float s = 0.f;
      for (int k = 0; k < 64; ++k) s += Bs[k * 64 + tid];
      b1o[n0 + tid] = b1e[n0 + tid] - s;
    }
  } else {
    // hred inline: self-contained 16x16 tile of H_{ch+1} -> next-chunk G state
    float* Ewt = smem;          // 1024
    float* KKs = smem + 1024;   // 16*65 = 1040
    float* b1l = smem + 2064;   // 16
    int bh = blk - 40;          // 0..127
    int m0 = (bh >> 5) * 16;
    int c0 = (bh & 31) * 16;
    #pragma unroll
    for (int q = 0; q < 4; ++q) {
      int e = q * 256 + tid;
      int i = e >> 4, cl = e & 15;
      size_t off = (size_t)i * 512 + c0 + cl;
      float s = 0.f;
      #pragma unroll
      for (int sl = 0; sl < 7; ++sl) s += Esl[(size_t)sl * 32768 + off];
      Ewt[i * 16 + cl] = s * GpC[off];
    }
    const float* KK = KKf + (size_t)((ch + 1) * (ch + 2) / 2 + ch) * 4096;
    #pragma unroll
    for (int q = 0; q < 4; ++q) {
      int e = q * 256 + tid;
      int ml = e >> 6, i = e & 63;
      KKs[ml * 65 + i] = KK[(m0 + ml) * 64 + i];
    }
    __syncthreads();
    if (tid < 16) {
      float s = 0.f;
      for (int i = 0; i < 64; ++i) s += Ewt[i * 16 + tid];
      b1l[tid] = b1e[c0 + tid] - s;
    }
    __syncthreads();
    int ml = tid >> 4, cl = tid & 15;
    int m = m0 + ml, c = c0 + cl;
    float corr = 0.f;
    #pragma unroll 16
    for (int i = 0; i < 64; ++i) corr += KKs[ml * 65 + i] * Ewt[i * 16 + cl];
    size_t off = (size_t)m * 512 + c;
    float s = Hbase_n[off] - corr;
    for (int j = 0; j < ch; ++j) s -= Hcorr[(size_t)j * 32768 + off];
    HhN[off] = s;
    float g, gp;
    gelu_both(s + b1l[cl], g, gp);
    GbN[off] = f2bf(g);
    GtbN[(size_t)c * 64 + m] = f2bf(g);
    GpN[off] = gp;
  }
}

// ========== stage 3: Y->out (49) || pred_{ch+1}->Dw+b2' (49, ch<7) || Hcorr ch+2 (8*(ch+1), ch<6) ==========
__global__ __launch_bounds__(256) void yp3_kernel(
    const ushort* __restrict__ G2b, const ushort* __restrict__ W2tb,
    const float* __restrict__ b2n, float* __restrict__ out, int t0,
    const ushort* __restrict__ Gnb, const float* __restrict__ Vn, float wc2,
    float* __restrict__ b2out, ushort* __restrict__ Dwb, ushort* __restrict__ Dwtb,
    const float* __restrict__ KKf, int ch,
    const float* __restrict__ Ewst, float* __restrict__ Hcorr) {
  __shared__ float smem[8192];
  int b = blockIdx.x;
  if (b < 49) {
    f32x4 acc[4] = {{0.f,0.f,0.f,0.f},{0.f,0.f,0.f,0.f},{0.f,0.f,0.f,0.f},{0.f,0.f,0.f,0.f}};
    int n0 = b * 64;
    nt64_core(G2b, 512, W2tb + (size_t)n0 * 512, 512, 16, acc);
    int lane = threadIdx.x & 63, wvv = threadIdx.x >> 6;
    int r0 = (wvv >> 1) * 32 + ((lane >> 4) << 2);
    int c0 = (wvv & 1) * 32 + (lane & 15);
    #pragma unroll
    for (int r = 0; r < 4; ++r) {
      #pragma unroll
      for (int p = 0; p < 4; ++p) {
        int m = r0 + r + ((p >> 1) ? 16 : 0);
        int d = n0 + c0 + ((p & 1) ? 16 : 0);
        out[(size_t)(t0 + m) * DM + d] = acc[p][r] + b2n[d];
      }
    }
  } else if (ch < 7 && b < 98) {
    f32x4 acc[4] = {{0.f,0.f,0.f,0.f},{0.f,0.f,0.f,0.f},{0.f,0.f,0.f,0.f},{0.f,0.f,0.f,0.f}};
    int n0 = (b - 49) * 64;
    nt64_core(Gnb, 512, W2tb + (size_t)n0 * 512, 512, 16, acc);
    dw_epilogue256(acc, n0, Vn, b2n, wc2, Dwb, Dwtb, b2out, smem);
  } else {
    int j2 = b - (ch < 7 ? 98 : 49);
    int j = j2 >> 3, bx = j2 & 7;      // j <= ch, corrections for chunk ch+2
    int trin = (ch + 2) * (ch + 3) / 2;
    hs_corr_job(KKf + (size_t)(trin + j) * 4096, Ewst + (size_t)j * 32768,
                Hcorr + (size_t)j * 32768, bx, smem);
  }
}

extern "C" void kernel_launch(void* const* d_in, const int* in_sizes, int n_in,
                              void* d_out, int out_size, void* d_ws, size_t ws_size,
                              hipStream_t stream) {
  const float* x  = (const float*)d_in[0];
  const float* wk = (const float*)d_in[1];
  const float* bk = (const float*)d_in[2];
  const float* wv = (const float*)d_in[3];
  const float* bv = (const float*)d_in[4];
  const float* sk = (const float*)d_in[5];
  const float* sv = (const float*)d_in[6];
  const float* W1 = (const float*)d_in[7];
  const float* b1 = (const float*)d_in[8];
  const float* W2 = (const float*)d_in[9];
  const float* b2 = (const float*)d_in[10];
  float* out = (float*)d_out;
  float* ws  = (float*)d_ws;

  // workspace layout (float units) — R7 minus the fp32 W2 masters
  ushort* nkb   = (ushort*)ws;                       // 802816 f
  ushort* w1tb  = (ushort*)(ws + 802816);            // 802816 f
  float* nv     = ws + 1605632;                      // 1605632
  float* bf_base = nv + 1605632;
  ushort* W2b0  = (ushort*)bf_base;                  // 802816 f
  ushort* W2tb0 = (ushort*)(bf_base + 802816);       // 802816 f
  ushort* W2bA  = (ushort*)(bf_base + 1605632);      // 802816 f
  ushort* W2bB  = (ushort*)(bf_base + 2408448);      // 802816 f
  ushort* W2tbA = (ushort*)(bf_base + 3211264);      // 802816 f
  ushort* W2tbB = (ushort*)(bf_base + 4014080);      // 802816 f
  float* Esl    = bf_base + 4816896;                 // 229376 (7 x 32768)
  float* Hb_sl  = Esl + 229376;                      // 1835008 (7 x 262144)
  float* KKsl   = Hb_sl + 1835008;                   // 1032192 (36 x 7 x 4096)
  float* Hbase  = KKsl + 1032192;                    // 262144
  float* KKf    = Hbase + 262144;                    // 147456
  float* HhA    = KKf + 147456;                      // 32768
  float* HhB    = HhA + 32768;                       // 32768
  float* GpA    = HhB + 32768;                       // 32768
  float* GpB    = GpA + 32768;                       // 32768
  ushort* GbA   = (ushort*)(GpB + 32768);            // 16384 f
  ushort* GbB   = (ushort*)(GpB + 49152);            // 16384 f
  ushort* GtbA  = (ushort*)(GpB + 65536);            // 16384 f
  ushort* GtbB  = (ushort*)(GpB + 81920);            // 16384 f
  ushort* G2b   = (ushort*)(GpB + 98304);            // 16384 f
  ushort* Dwb   = (ushort*)(GpB + 114688);           // 100352 f
  ushort* Dwtb  = (ushort*)(GpB + 215040);           // 100352 f
  float* Ewst   = GpB + 315392;                      // 262144 (8 x 32768)
  float* Hcorr  = Ewst + 262144;                     // 229376 (7 x 32768)
  float* b1A    = Hcorr + 229376;                    // 512
  float* b1B    = b1A + 512;                         // 512
  float* b2A    = b1B + 512;                         // 3136
  float* b2B    = b2A + 3136;                        // 3136

  ushort* W2bb[2]   = { W2bA, W2bB };
  ushort* W2tbb[2]  = { W2tbA, W2tbB };
  ushort* Gbb[2]    = { GbA, GbB };
  ushort* Gtbb[2]   = { GtbA, GtbB };
  float* Hhb[2]     = { HhA, HhB };
  float* Gpb[2]     = { GpA, GpB };
  float* b1buf[2]   = { b1A, b1B };
  float* b2buf[2]   = { b2A, b2B };

  // weights[i] = ETA0 * ALPHA^i * (ALPHA^63 / ALPHA^i) = ETA0 * ALPHA^63 (constant)
  float wc2 = 2.0f * (float)(0.1 * pow(0.9, 63.0));

  conv_rms<<<2352, 256, 0, stream>>>(x, wk, bk, wv, bv, sk, sv,
                                     W1, w1tb, W2, W2b0, W2tb0, nkb, nv);
  u1_kernel<<<700, 256, 0, stream>>>(nkb, w1tb, KKsl, Hb_sl);
  u2_kernel<<<1600, 256, 0, stream>>>(KKsl, Hb_sl, KKf, Hbase, b1, HhA, GbA, GtbA, GpA);
  pred0_kernel<<<49, 256, 0, stream>>>(GbA, W2tb0, nv, b2, wc2, b2A, Dwb, Dwtb);

  for (int ch = 0; ch < 8; ++ch) {
    const float* b1e  = ch ? b1buf[(ch - 1) & 1] : b1;
    const ushort* W2b_c = ch ? W2bb[(ch - 1) & 1] : W2b0;

    // stage 1: E slices || W2 update (bf16 master + transposed shadow)
    p4w2_kernel<<<448, 256, 0, stream>>>(
        Dwb, Dwtb, Gtbb[ch & 1], W2b_c,
        W2bb[ch & 1], W2tbb[ch & 1], Esl);
    // stage 2: G2 stripes || hsEw (Ew + b1') || hred inline -> chunk ch+1 state
    g2hr_kernel<<<(ch < 7 ? 168 : 32), 256, 0, stream>>>(
        KKf, ch, Esl, Gpb[ch & 1], Hhb[ch & 1], b1e, b1buf[ch & 1],
        G2b, Ewst + (size_t)ch * 32768,
        Hcorr, Hbase + (size_t)((ch + 1) & 7) * 32768,
        Hhb[(ch + 1) & 1], Gbb[(ch + 1) & 1], Gtbb[(ch + 1) & 1], Gpb[(ch + 1) & 1]);
    // stage 3: Y -> out || pred_{ch+1} -> Dw + b2' || Hcorr for ch+2
    int g3 = 49 + (ch < 7 ? 49 : 0) + (ch < 6 ? 8 * (ch + 1) : 0);
    yp3_kernel<<<g3, 256, 0, stream>>>(
        G2b, W2tbb[ch & 1], b2buf[ch & 1], out, ch * 64,
        Gbb[(ch + 1) & 1], nv + (size_t)((ch + 1) & 7) * 200704, wc2,
        b2buf[(ch + 1) & 1], Dwb, Dwtb,
        KKf, ch, Ewst, Hcorr);
  }
}